// Round 1
// baseline (1086.908 us; speedup 1.0000x reference)
//
#include <hip/hip_runtime.h>
#include <hip/hip_bf16.h>

typedef __attribute__((ext_vector_type(8))) short short8;
typedef __attribute__((ext_vector_type(4))) float f32x4;

#define NWIN 2048
#define K2v  49
#define CD   512
#define TPB  512
#define SCALE_F 0.17677669529663687f

#define LDS_X   0u
#define LDS_V   50176u
#define LDS_QK  100352u
#define LDS_RPB 150528u
#define LDS_PW  50176u
#define LDS_EM  0u
#define LDS_TOTAL 155936

__device__ __forceinline__ unsigned short f2bf(float f){
  union { float f; unsigned u; } x; x.f = f;
  unsigned r = x.u + 0x7fffu + ((x.u >> 16) & 1u);
  return (unsigned short)(r >> 16);
}
__device__ __forceinline__ float bf2f(unsigned short u){
  union { float f; unsigned u; } x; x.u = ((unsigned)u) << 16; return x.f;
}
// XOR-swizzled LDS byte address: rows of `rowb` bytes, 16B-chunk swizzle by row&7
__device__ __forceinline__ unsigned swz(unsigned base, int row, unsigned rowb, unsigned colb){
  return base + (unsigned)row * rowb + (colb ^ (((unsigned)row & 7u) << 4));
}

// OUT[49->64 x 64strip] = A(lds,[49x512]bf16,swz) @ W^T rows [wrow0, wrow0+64)
__device__ __forceinline__ void gemm_strip(const unsigned char* ldsp, unsigned abase,
    const unsigned short* __restrict__ W, int wrow0, int l15, int lg, f32x4 acc[4][4]){
  for (int kk = 0; kk < 16; kk++){
    short8 bq[4];
#pragma unroll
    for (int nt = 0; nt < 4; nt++){
      const unsigned short* p = W + (size_t)(wrow0 + nt*16 + l15) * CD + kk*32 + lg*8;
      bq[nt] = *(const short8*)p;
    }
    short8 aq[4];
#pragma unroll
    for (int mt = 0; mt < 4; mt++){
      int r = mt*16 + l15; if (r > 48) r = 48;
      aq[mt] = *(const short8*)(ldsp + swz(abase, r, 1024u, (unsigned)(kk*64 + lg*16)));
    }
#pragma unroll
    for (int mt = 0; mt < 4; mt++)
#pragma unroll
      for (int nt = 0; nt < 4; nt++)
        acc[mt][nt] = __builtin_amdgcn_mfma_f32_16x16x32_bf16(aq[mt], bq[nt], acc[mt][nt], 0, 0, 0);
  }
}

__global__ void conv_w(const float* __restrict__ a, const float* __restrict__ b,
                       const float* __restrict__ c, const float* __restrict__ d,
                       unsigned short* __restrict__ o){
  int i = blockIdx.x * 256 + threadIdx.x;
  if (i < 524288)        o[i] = f2bf(a[i]);
  else if (i < 786432)   o[i] = f2bf(b[i - 524288]);
  else if (i < 1310720)  o[i] = f2bf(c[i - 786432]);
  else                   o[i] = f2bf(d[i - 1310720]);
}

__launch_bounds__(TPB, 2)
__global__ void wa_main(
    const float* __restrict__ x,
    const float* __restrict__ qk_b,
    const float* __restrict__ rev_v_b,
    const float* __restrict__ proj_b,
    const float* __restrict__ rpb,
    const unsigned short* __restrict__ Wqk,
    const unsigned short* __restrict__ Wv,
    const unsigned short* __restrict__ Wwg,
    const unsigned short* __restrict__ Wproj,
    float* __restrict__ out)
{
  __shared__ __align__(16) unsigned char ldsp[LDS_TOTAL];
  const int tid  = threadIdx.x;
  const int wave = tid >> 6;
  const int lane = tid & 63;
  const int l15  = lane & 15;
  const int lg   = lane >> 4;
  const int b    = blockIdx.x;
  const float* xb = x + (size_t)b * K2v * CD;
  const f32x4 zf = {0.f, 0.f, 0.f, 0.f};

  // ---- stage rpb table (bf16) ----
  for (int i = tid; i < 169*16; i += TPB)
    *(unsigned short*)(ldsp + LDS_RPB + i*2) = f2bf(rpb[i]);
  // ---- stage x -> bf16 LDS (swizzled) ----
  for (int ch = tid; ch < K2v*64; ch += TPB){
    int r = ch >> 6, c8 = ch & 63;
    const f32x4* s = (const f32x4*)(xb + r*CD + c8*8);
    f32x4 lo = s[0], hi = s[1];
    short8 v;
    v[0]=f2bf(lo[0]); v[1]=f2bf(lo[1]); v[2]=f2bf(lo[2]); v[3]=f2bf(lo[3]);
    v[4]=f2bf(hi[0]); v[5]=f2bf(hi[1]); v[6]=f2bf(hi[2]); v[7]=f2bf(hi[3]);
    *(short8*)(ldsp + swz(LDS_X, r, 1024u, (unsigned)(c8*16))) = v;
  }
  __syncthreads();

  // ---- V = x @ Wv^T + b, bf16 swizzled into LDS_V ----
  {
    f32x4 acc[4][4];
#pragma unroll
    for (int mt=0; mt<4; mt++)
#pragma unroll
      for (int nt=0; nt<4; nt++) acc[mt][nt] = zf;
    gemm_strip(ldsp, LDS_X, Wv, wave*64, l15, lg, acc);
#pragma unroll
    for (int nt=0; nt<4; nt++){
      int ch = wave*64 + nt*16 + l15;
      float bias = rev_v_b[ch];
#pragma unroll
      for (int mt=0; mt<4; mt++)
#pragma unroll
        for (int i=0; i<4; i++){
          int r = mt*16 + lg*4 + i;
          if (r < K2v)
            *(unsigned short*)(ldsp + swz(LDS_V, r, 1024u, (unsigned)(ch*2))) = f2bf(acc[mt][nt][i] + bias);
        }
    }
  }

  // ---- QK pass GEMM: 8 heads per pass into LDS_QK [49][512] (q cols 0-255, k cols 256-511)
  auto qk_pass = [&](int p){
    f32x4 acc[4][4];
#pragma unroll
    for (int mt=0; mt<4; mt++)
#pragma unroll
      for (int nt=0; nt<4; nt++) acc[mt][nt] = zf;
    int wrow0 = (wave < 4) ? (p*256 + wave*64) : (512 + p*256 + (wave-4)*64);
    gemm_strip(ldsp, LDS_X, Wqk, wrow0, l15, lg, acc);
#pragma unroll
    for (int nt=0; nt<4; nt++){
      int ch  = wrow0 + nt*16 + l15;       // actual qk channel (bias index)
      int col = wave*64 + nt*16 + l15;     // column inside region
      float bias = qk_b[ch];
#pragma unroll
      for (int mt=0; mt<4; mt++)
#pragma unroll
        for (int i=0; i<4; i++){
          int r = mt*16 + lg*4 + i;
          if (r < K2v)
            *(unsigned short*)(ldsp + swz(LDS_QK, r, 1024u, (unsigned)(col*2))) = f2bf(acc[mt][nt][i] + bias);
        }
    }
  };

  // ---- attention for one pass: wave handles head h = p*8+wave; accumulates em[4][2]
  auto attn_pass = [&](int p, f32x4 (&em)[4][2]){
    const int h = p*8 + wave;
    // S = q @ k^T  (K = E = 32, single k-step)
    f32x4 s[4][4];
#pragma unroll
    for (int mt=0; mt<4; mt++)
#pragma unroll
      for (int nt=0; nt<4; nt++) s[mt][nt] = zf;
    short8 aq[4], bq[4];
#pragma unroll
    for (int mt=0; mt<4; mt++){
      int r = mt*16 + l15; if (r > 48) r = 48;
      aq[mt] = *(const short8*)(ldsp + swz(LDS_QK, r, 1024u, (unsigned)(wave*64 + lg*16)));
    }
#pragma unroll
    for (int nt=0; nt<4; nt++){
      int kt = nt*16 + l15; if (kt > 48) kt = 48;
      bq[nt] = *(const short8*)(ldsp + swz(LDS_QK, kt, 1024u, (unsigned)(512 + wave*64 + lg*16)));
    }
#pragma unroll
    for (int mt=0; mt<4; mt++)
#pragma unroll
      for (int nt=0; nt<4; nt++)
        s[mt][nt] = __builtin_amdgcn_mfma_f32_16x16x32_bf16(aq[mt], bq[nt], s[mt][nt], 0, 0, 0);
    // scale + rel-pos bias + mask padded key cols
#pragma unroll
    for (int mt=0; mt<4; mt++)
#pragma unroll
      for (int nt=0; nt<4; nt++)
#pragma unroll
        for (int i=0; i<4; i++){
          int q  = mt*16 + lg*4 + i;
          int kt = nt*16 + l15;
          float v = s[mt][nt][i] * SCALE_F;
          if (kt < K2v){
            int qc = (q > 48) ? 48 : q;
            int qi = qc / 7, qj = qc - qi*7;
            int ki = kt / 7, kj = kt - ki*7;
            int idx = (qi - ki + 6)*13 + (qj - kj + 6);
            v += bf2f(*(const unsigned short*)(ldsp + LDS_RPB + (idx*16 + h)*2));
          } else v = -1e30f;
          s[mt][nt][i] = v;
        }
    // softmax over key dim (cols: 4 nt regs x 16 lanes within lg-group)
#pragma unroll
    for (int mt=0; mt<4; mt++)
#pragma unroll
      for (int i=0; i<4; i++){
        float m = fmaxf(fmaxf(s[mt][0][i], s[mt][1][i]), fmaxf(s[mt][2][i], s[mt][3][i]));
        m = fmaxf(m, __shfl_xor(m, 1)); m = fmaxf(m, __shfl_xor(m, 2));
        m = fmaxf(m, __shfl_xor(m, 4)); m = fmaxf(m, __shfl_xor(m, 8));
        float sum = 0.f;
#pragma unroll
        for (int nt=0; nt<4; nt++){ float e = __expf(s[mt][nt][i] - m); s[mt][nt][i] = e; sum += e; }
        sum += __shfl_xor(sum, 1); sum += __shfl_xor(sum, 2);
        sum += __shfl_xor(sum, 4); sum += __shfl_xor(sum, 8);
        float inv = 1.0f / sum;
#pragma unroll
        for (int nt=0; nt<4; nt++) s[mt][nt][i] *= inv;
      }
    __syncthreads();   // all waves done reading q/k from LDS_QK
    // store P transposed into per-wave scratch: PT[kt'][q'] = P[q'][kt'], zero padded q'
    const unsigned ptb = LDS_QK + (unsigned)wave * 6272u;
#pragma unroll
    for (int mt=0; mt<4; mt++)
#pragma unroll
      for (int nt=0; nt<4; nt++)
#pragma unroll
        for (int i=0; i<4; i++){
          int q  = mt*16 + lg*4 + i;
          int kt = nt*16 + l15;
          if (kt < K2v){
            unsigned short val = (q < K2v) ? f2bf(s[mt][nt][i]) : (unsigned short)0;
            *(unsigned short*)(ldsp + ptb + (unsigned)kt*128u + (((unsigned)(q*2)) ^ (((unsigned)kt & 7u) << 4))) = val;
          }
        }
    // em += P^T @ V_head   (A[q][k] = P[k][q] from PT; B[k][e] gathered from LDS_V, row-clamped)
#pragma unroll
    for (int kk=0; kk<2; kk++){
      short8 pa[4];
#pragma unroll
      for (int mt=0; mt<4; mt++){
        int r = mt*16 + l15; if (r > 48) r = 48;
        pa[mt] = *(const short8*)(ldsp + ptb + (unsigned)r*128u + (((unsigned)(kk*64 + lg*16)) ^ (((unsigned)r & 7u) << 4)));
      }
      short8 vb[2];
#pragma unroll
      for (int nt=0; nt<2; nt++){
        int ch = h*32 + nt*16 + l15;
#pragma unroll
        for (int j=0; j<8; j++){
          int kt = kk*32 + lg*8 + j; if (kt > 48) kt = 48;
          vb[nt][j] = *(const short*)(ldsp + swz(LDS_V, kt, 1024u, (unsigned)(ch*2)));
        }
      }
#pragma unroll
      for (int mt=0; mt<4; mt++)
#pragma unroll
        for (int nt=0; nt<2; nt++)
          em[mt][nt] = __builtin_amdgcn_mfma_f32_16x16x32_bf16(pa[mt], vb[nt], em[mt][nt], 0, 0, 0);
    }
  };

  f32x4 em0[4][2], em1[4][2];
#pragma unroll
  for (int mt=0; mt<4; mt++)
#pragma unroll
    for (int nt=0; nt<2; nt++){ em0[mt][nt] = zf; em1[mt][nt] = zf; }

  qk_pass(0);
  __syncthreads();
  attn_pass(0, em0);
  __syncthreads();
  qk_pass(1);
  __syncthreads();
  attn_pass(1, em1);
  __syncthreads();

  // ---- PW = x @ Wwg^T, stored per-token (e,f)-permuted into LDS_PW [49][1024] ----
  for (int nh = 0; nh < 2; nh++){
    f32x4 acc[4][4];
#pragma unroll
    for (int mt=0; mt<4; mt++)
#pragma unroll
      for (int nt=0; nt<4; nt++) acc[mt][nt] = zf;
    int n0 = nh*512 + wave*64;
    gemm_strip(ldsp, LDS_X, Wwg, n0, l15, lg, acc);
#pragma unroll
    for (int nt=0; nt<4; nt++){
      int n  = n0 + nt*16 + l15;                  // wg channel = e*32 + f
      int pc = (n & 31)*32 + (n >> 5);            // permuted col = f*32 + e
      unsigned cb = ((unsigned)(pc*2)) ^ (((unsigned)n & 7u) << 4);
#pragma unroll
      for (int mt=0; mt<4; mt++)
#pragma unroll
        for (int i=0; i<4; i++){
          int r = mt*16 + lg*4 + i;
          if (r < K2v)
            *(unsigned short*)(ldsp + LDS_PW + (unsigned)r*2048u + cb) = f2bf(acc[mt][nt][i]);
        }
    }
  }
  __syncthreads();   // PW written; all X reads done -> reuse LDS_X region for em

  // ---- dump em (both heads of this wave) to LDS_EM [49][512] (ch = h*32+e) ----
  auto em_store = [&](f32x4 (&em)[4][2], int h){
#pragma unroll
    for (int mt=0; mt<4; mt++)
#pragma unroll
      for (int nt=0; nt<2; nt++)
#pragma unroll
        for (int i=0; i<4; i++){
          int q = mt*16 + lg*4 + i;
          if (q < K2v){
            int ch = h*32 + nt*16 + l15;
            *(unsigned short*)(ldsp + swz(LDS_EM, q, 1024u, (unsigned)(ch*2))) = f2bf(em[mt][nt][i]);
          }
        }
  };
  em_store(em0, wave);
  em_store(em1, 8 + wave);
  __syncthreads();

  // ---- hypernet: per token t: out1[h][f] = sum_e em[h][e] * PW_t[e][f]; in-place over em ----
  for (int t = wave; t < K2v; t += 8){
    short8 ea = *(const short8*)(ldsp + swz(LDS_EM, t, 1024u, (unsigned)(l15*64 + lg*16)));
    f32x4 o[2];
#pragma unroll
    for (int nt=0; nt<2; nt++){
      int f = nt*16 + l15;
      short8 pb = *(const short8*)(ldsp + LDS_PW + (unsigned)t*2048u +
                    (((unsigned)((f*32 + lg*8)*2)) ^ (((unsigned)f & 7u) << 4)));
      o[nt] = __builtin_amdgcn_mfma_f32_16x16x32_bf16(ea, pb, zf, 0, 0, 0);
    }
#pragma unroll
    for (int nt=0; nt<2; nt++)
#pragma unroll
      for (int i=0; i<4; i++){
        int h2 = lg*4 + i;
        int ch = h2*32 + nt*16 + l15;
        *(unsigned short*)(ldsp + swz(LDS_EM, t, 1024u, (unsigned)(ch*2))) = f2bf(o[nt][i]);
      }
  }
  __syncthreads();

  // ---- final: out = out1 @ Wproj^T + proj_b (fp32 to global) ----
  {
    f32x4 acc[4][4];
#pragma unroll
    for (int mt=0; mt<4; mt++)
#pragma unroll
      for (int nt=0; nt<4; nt++) acc[mt][nt] = zf;
    gemm_strip(ldsp, LDS_EM, Wproj, wave*64, l15, lg, acc);
    float* ob = out + (size_t)b * K2v * CD;
#pragma unroll
    for (int nt=0; nt<4; nt++){
      int n = wave*64 + nt*16 + l15;
      float bias = proj_b[n];
#pragma unroll
      for (int mt=0; mt<4; mt++)
#pragma unroll
        for (int i=0; i<4; i++){
          int r = mt*16 + lg*4 + i;
          if (r < K2v) ob[r*CD + n] = acc[mt][nt][i] + bias;
        }
    }
  }
}

extern "C" void kernel_launch(void* const* d_in, const int* in_sizes, int n_in,
                              void* d_out, int out_size, void* d_ws, size_t ws_size,
                              hipStream_t stream){
  const float* x       = (const float*)d_in[0];
  const float* qk_w    = (const float*)d_in[1];
  const float* qk_b    = (const float*)d_in[2];
  const float* rev_v_w = (const float*)d_in[3];
  const float* rev_v_b = (const float*)d_in[4];
  const float* wg_w    = (const float*)d_in[5];
  const float* proj_w  = (const float*)d_in[6];
  const float* proj_b  = (const float*)d_in[7];
  const float* rpb     = (const float*)d_in[8];
  unsigned short* w = (unsigned short*)d_ws;

  conv_w<<<6144, 256, 0, stream>>>(qk_w, rev_v_w, wg_w, proj_w, w);
  wa_main<<<NWIN, TPB, 0, stream>>>(x, qk_b, rev_v_b, proj_b, rpb,
      w, w + 524288, w + 786432, w + 1310720, (float*)d_out);
}

// Round 2
// 812.632 us; speedup vs baseline: 1.3375x; 1.3375x over previous
//
#include <hip/hip_runtime.h>
#include <hip/hip_bf16.h>
#include <stdint.h>

typedef __attribute__((ext_vector_type(8))) short short8;
typedef __attribute__((ext_vector_type(4))) float f32x4;
typedef unsigned short u16;

#define SCALE_F 0.17677669529663687f

__device__ __forceinline__ u16 f2bf(float f){
  union { float f; unsigned u; } x; x.f = f;
  unsigned r = x.u + 0x7fffu + ((x.u >> 16) & 1u);
  return (u16)(r >> 16);
}
__device__ __forceinline__ float bf2f(u16 u){
  union { float f; unsigned u; } x; x.u = ((unsigned)u) << 16; return x.f;
}
// XOR-swizzled LDS byte address within a row (rowb bytes/row)
__device__ __forceinline__ unsigned swz(unsigned base, int row, unsigned rowb, unsigned colb){
  return base + (unsigned)row * rowb + (colb ^ (((unsigned)row & 7u) << 4));
}
// async global->LDS 16B (CK-style addrspace casts via integer)
__device__ __forceinline__ void gll16(const void* g, void* l){
  __builtin_amdgcn_global_load_lds(
    (const __attribute__((address_space(1))) unsigned int*)(unsigned long long)(size_t)g,
    (__attribute__((address_space(3))) unsigned int*)(unsigned int)(size_t)l,
    16, 0, 0);
}

// =====================================================================
// conv: W (qk|v|wg|proj -> Wcat layout) + x, fp32 -> bf16 into ws
// 6,619,136 chunks of 8 elements = 25856 blocks x 256 threads exactly
__global__ void convk(const float* __restrict__ x,
                      const float* __restrict__ qk_w, const float* __restrict__ rev_v_w,
                      const float* __restrict__ wg_w, const float* __restrict__ proj_w,
                      u16* __restrict__ ws){
  long long i8 = ((long long)blockIdx.x * 256 + threadIdx.x) * 8;
  const float* s;
  if      (i8 <  524288) s = qk_w   + i8;
  else if (i8 <  786432) s = rev_v_w + (i8 - 524288);
  else if (i8 < 1310720) s = wg_w   + (i8 - 786432);
  else if (i8 < 1572864) s = proj_w + (i8 - 1310720);
  else                   s = x      + (i8 - 1572864);
  f32x4 lo = *(const f32x4*)s, hi = *(const f32x4*)(s + 4);
  short8 v;
  v[0]=f2bf(lo[0]); v[1]=f2bf(lo[1]); v[2]=f2bf(lo[2]); v[3]=f2bf(lo[3]);
  v[4]=f2bf(hi[0]); v[5]=f2bf(hi[1]); v[6]=f2bf(hi[2]); v[7]=f2bf(hi[3]);
  *(short8*)(ws + i8) = v;
}

// =====================================================================
// 128x128-tile GEMM (m97 structure): C[M x NT*128] = A[M x 512] @ B^T, B=[NT*128][512]
// K=512, BK=64, 4 waves, global_load_lds staging with pre-swizzled source.
// F32OUT=0: bf16 out + (qk_b|rev_v_b|0) bias by col range. F32OUT=1: fp32 out + b0 bias.
template<int NT, int F32OUT>
__global__ __launch_bounds__(256, 2)
void gemm128(const u16* __restrict__ A, int lda,
             const u16* __restrict__ B,
             const float* __restrict__ b0, const float* __restrict__ b1,
             void* __restrict__ Cg, int ldc){
  __shared__ __align__(16) unsigned char sm[32768];   // A 16K | B 16K (C restage reuses)
  const int tid = threadIdx.x, wave = tid >> 6, lane = tid & 63;
  const int l15 = lane & 15, lg = lane >> 4;
  // bijective XCD swizzle (m204)
  const int nwg = gridDim.x, bidr = blockIdx.x;
  const int q8 = nwg >> 3, r8 = nwg & 7, xc = bidr & 7, oo = bidr >> 3;
  const int wg = (xc < r8 ? xc * (q8 + 1) : r8 * (q8 + 1) + (xc - r8) * q8) + oo;
  const int bm = wg / NT, bn = wg % NT;
  const int wm = wave >> 1, wn = wave & 1;
  const f32x4 zf = {0.f, 0.f, 0.f, 0.f};
  f32x4 acc[4][4];
#pragma unroll
  for (int mt=0; mt<4; mt++)
#pragma unroll
    for (int nt=0; nt<4; nt++) acc[mt][nt] = zf;

  const u16* Ab = A + (size_t)bm * 128 * lda;
  const u16* Bb = B + (size_t)bn * 128 * 512;
  const int r0 = ((wave*4)*64 + lane) >> 3;      // helper consts folded below

  for (int ks = 0; ks < 8; ks++){
#pragma unroll
    for (int it = 0; it < 4; it++){
      int c = (wave*4 + it)*64 + lane;           // chunk 0..1023
      int r = c >> 3, cc = c & 7;
      int sc = cc ^ (r & 7);                     // pre-swizzled source chunk
      gll16(Ab + (size_t)r*lda + ks*64 + sc*8, sm + (unsigned)(wave*4 + it)*1024u);
      gll16(Bb + (size_t)r*512 + ks*64 + sc*8, sm + 16384u + (unsigned)(wave*4 + it)*1024u);
    }
    __syncthreads();
#pragma unroll
    for (int kk = 0; kk < 2; kk++){
      short8 aq[4], bq[4];
#pragma unroll
      for (int mt=0; mt<4; mt++){
        int r = wm*64 + mt*16 + l15;
        aq[mt] = *(const short8*)(sm + (unsigned)r*128u + (((unsigned)(kk*64 + lg*16)) ^ (((unsigned)r & 7u) << 4)));
      }
#pragma unroll
      for (int nt=0; nt<4; nt++){
        int r = wn*64 + nt*16 + l15;
        bq[nt] = *(const short8*)(sm + 16384u + (unsigned)r*128u + (((unsigned)(kk*64 + lg*16)) ^ (((unsigned)r & 7u) << 4)));
      }
#pragma unroll
      for (int mt=0; mt<4; mt++)
#pragma unroll
        for (int nt=0; nt<4; nt++)
          acc[mt][nt] = __builtin_amdgcn_mfma_f32_16x16x32_bf16(aq[mt], bq[nt], acc[mt][nt], 0, 0, 0);
    }
    __syncthreads();
  }
  (void)r0;

  float bia[4];
#pragma unroll
  for (int nt=0; nt<4; nt++){
    int n = bn*128 + wn*64 + nt*16 + l15;
    if (F32OUT) bia[nt] = b0[n];
    else        bia[nt] = (n < 1024) ? b0[n] : (n < 1536 ? b1[n - 1024] : 0.f);
  }

  if (!F32OUT){
    // bf16 C restage through LDS -> coalesced 16B stores
#pragma unroll
    for (int mt=0; mt<4; mt++)
#pragma unroll
      for (int nt=0; nt<4; nt++)
#pragma unroll
        for (int i=0; i<4; i++){
          int row = wm*64 + mt*16 + lg*4 + i;
          unsigned colb = (unsigned)((wn*64 + nt*16 + l15) * 2);
          *(u16*)(sm + (unsigned)row*256u + (colb ^ (((unsigned)row & 7u) << 4))) = f2bf(acc[mt][nt][i] + bia[nt]);
        }
    __syncthreads();
    u16* Co = (u16*)Cg;
#pragma unroll
    for (int it=0; it<8; it++){
      int c = it*256 + tid;
      int r = c >> 4, cc = c & 15;
      short8 v = *(const short8*)(sm + (unsigned)r*256u + (((unsigned)(cc*16)) ^ (((unsigned)r & 7u) << 4)));
      *(short8*)(Co + (size_t)(bm*128 + r)*ldc + bn*128 + cc*8) = v;
    }
  } else {
    // fp32 C restage in two 64-row halves (32KB each)
    float* Co = (float*)Cg;
#pragma unroll
    for (int half=0; half<2; half++){
      if (wm == half){
#pragma unroll
        for (int mt=0; mt<4; mt++)
#pragma unroll
          for (int nt=0; nt<4; nt++)
#pragma unroll
            for (int i=0; i<4; i++){
              int row = mt*16 + lg*4 + i;
              unsigned colb = (unsigned)((wn*64 + nt*16 + l15) * 4);
              *(float*)(sm + (unsigned)row*512u + (colb ^ (((unsigned)row & 7u) << 4))) = acc[mt][nt][i] + bia[nt];
            }
      }
      __syncthreads();
#pragma unroll
      for (int it=0; it<8; it++){
        int c = it*256 + tid;
        int r = c >> 5, cc = c & 31;
        f32x4 v = *(const f32x4*)(sm + (unsigned)r*512u + (((unsigned)(cc*16)) ^ (((unsigned)r & 7u) << 4)));
        *(f32x4*)(Co + (size_t)(bm*128 + half*64 + r)*ldc + bn*128 + cc*4) = v;
      }
      __syncthreads();
    }
  }
}

// =====================================================================
// Attention per window, barrier-free. qkvpw rows [t][2560] = q|k|v|pw.
// 8 waves, wave handles heads {w, w+8}; PT scratch per-wave in LDS.
__global__ __launch_bounds__(512, 2)
void attn_k(const u16* __restrict__ qkv, const float* __restrict__ rpb,
            u16* __restrict__ em){
  __shared__ __align__(16) unsigned char pt[50176];
  const int tid = threadIdx.x, wave = tid >> 6, lane = tid & 63;
  const int l15 = lane & 15, lg = lane >> 4;
  const size_t wb = (size_t)blockIdx.x * 49;
  const u16* base = qkv + wb * 2560;
  u16* emb = em + wb * 512;
  unsigned char* ptb = pt + (unsigned)wave * 6272u;
  const f32x4 zf = {0.f, 0.f, 0.f, 0.f};

  for (int hp = 0; hp < 2; hp++){
    const int h = wave + hp*8;
    short8 aq[4], bq[4];
#pragma unroll
    for (int mt=0; mt<4; mt++){
      int r = mt*16 + l15; if (r > 48) r = 48;
      aq[mt] = *(const short8*)(base + (size_t)r*2560 + h*32 + lg*8);
    }
#pragma unroll
    for (int nt=0; nt<4; nt++){
      int kt = nt*16 + l15; if (kt > 48) kt = 48;
      bq[nt] = *(const short8*)(base + (size_t)kt*2560 + 512 + h*32 + lg*8);
    }
    f32x4 s[4][4];
#pragma unroll
    for (int mt=0; mt<4; mt++)
#pragma unroll
      for (int nt=0; nt<4; nt++) s[mt][nt] = zf;
#pragma unroll
    for (int mt=0; mt<4; mt++)
#pragma unroll
      for (int nt=0; nt<4; nt++)
        s[mt][nt] = __builtin_amdgcn_mfma_f32_16x16x32_bf16(aq[mt], bq[nt], s[mt][nt], 0, 0, 0);
    // scale + rel-pos bias + mask padded keys
#pragma unroll
    for (int mt=0; mt<4; mt++)
#pragma unroll
      for (int nt=0; nt<4; nt++)
#pragma unroll
        for (int i=0; i<4; i++){
          int q  = mt*16 + lg*4 + i;
          int kt = nt*16 + l15;
          float v = s[mt][nt][i] * SCALE_F;
          if (kt < 49){
            int qc = (q > 48) ? 48 : q;
            int qi = qc / 7, qj = qc - qi*7;
            int ki = kt / 7, kj = kt - ki*7;
            int idx = (qi - ki + 6)*13 + (qj - kj + 6);
            v += rpb[idx*16 + h];
          } else v = -1e30f;
          s[mt][nt][i] = v;
        }
    // wave-parallel softmax over key dim
#pragma unroll
    for (int mt=0; mt<4; mt++)
#pragma unroll
      for (int i=0; i<4; i++){
        float m = fmaxf(fmaxf(s[mt][0][i], s[mt][1][i]), fmaxf(s[mt][2][i], s[mt][3][i]));
        m = fmaxf(m, __shfl_xor(m, 1)); m = fmaxf(m, __shfl_xor(m, 2));
        m = fmaxf(m, __shfl_xor(m, 4)); m = fmaxf(m, __shfl_xor(m, 8));
        float sum = 0.f;
#pragma unroll
        for (int nt=0; nt<4; nt++){ float e = __expf(s[mt][nt][i] - m); s[mt][nt][i] = e; sum += e; }
        sum += __shfl_xor(sum, 1); sum += __shfl_xor(sum, 2);
        sum += __shfl_xor(sum, 4); sum += __shfl_xor(sum, 8);
        float inv = 1.0f / sum;
#pragma unroll
        for (int nt=0; nt<4; nt++) s[mt][nt][i] *= inv;
      }
    // store P transposed (PT[kt][q] = P[q][kt]); zero padded q rows
#pragma unroll
    for (int mt=0; mt<4; mt++)
#pragma unroll
      for (int nt=0; nt<4; nt++)
#pragma unroll
        for (int i=0; i<4; i++){
          int q  = mt*16 + lg*4 + i;
          int kt = nt*16 + l15;
          if (kt < 49){
            u16 val = (q < 49) ? f2bf(s[mt][nt][i]) : (u16)0;
            *(u16*)(ptb + (unsigned)kt*128u + (((unsigned)(q*2)) ^ (((unsigned)kt & 7u) << 4))) = val;
          }
        }
    // em = PT-as-A @ V_head
    f32x4 emv[4][2];
#pragma unroll
    for (int mt=0; mt<4; mt++)
#pragma unroll
      for (int nt=0; nt<2; nt++) emv[mt][nt] = zf;
#pragma unroll
    for (int kk=0; kk<2; kk++){
      short8 pa[4];
#pragma unroll
      for (int mt=0; mt<4; mt++){
        int r = mt*16 + l15; if (r > 48) r = 48;
        pa[mt] = *(const short8*)(ptb + (unsigned)r*128u + (((unsigned)(kk*64 + lg*16)) ^ (((unsigned)r & 7u) << 4)));
      }
      short8 vb[2];
#pragma unroll
      for (int nt=0; nt<2; nt++){
        int ch = 1024 + h*32 + nt*16 + l15;
#pragma unroll
        for (int j=0; j<8; j++){
          int kt = kk*32 + lg*8 + j; if (kt > 48) kt = 48;
          vb[nt][j] = *(const short*)(base + (size_t)kt*2560 + ch);
        }
      }
#pragma unroll
      for (int mt=0; mt<4; mt++)
#pragma unroll
        for (int nt=0; nt<2; nt++)
          emv[mt][nt] = __builtin_amdgcn_mfma_f32_16x16x32_bf16(pa[mt], vb[nt], emv[mt][nt], 0, 0, 0);
    }
#pragma unroll
    for (int mt=0; mt<4; mt++)
#pragma unroll
      for (int nt=0; nt<2; nt++)
#pragma unroll
        for (int i=0; i<4; i++){
          int q = mt*16 + lg*4 + i;
          if (q < 49)
            emb[(size_t)q*512 + h*32 + nt*16 + l15] = f2bf(emv[mt][nt][i]);
        }
  }
}

// =====================================================================
// Hypernet: per token t, out1[h][f] = sum_e em[h][e] * pw[e][f]; in-place over em.
__global__ __launch_bounds__(512, 2)
void hyper_k(const u16* __restrict__ qkvpw, u16* __restrict__ em){
  const int tid = threadIdx.x, wave = tid >> 6, lane = tid & 63;
  const int l15 = lane & 15, lg = lane >> 4;
  const size_t t = (size_t)blockIdx.x * 8 + wave;
  const u16* pwt = qkvpw + t*2560 + 1536;
  u16* emt = em + t*512;
  const f32x4 zf = {0.f, 0.f, 0.f, 0.f};
  short8 ea = *(const short8*)(emt + l15*32 + lg*8);
  f32x4 o[2];
#pragma unroll
  for (int nt=0; nt<2; nt++){
    short8 pb;
#pragma unroll
    for (int j=0; j<8; j++){
      int e = lg*8 + j;
      pb[j] = *(const short*)(pwt + e*32 + nt*16 + l15);
    }
    o[nt] = __builtin_amdgcn_mfma_f32_16x16x32_bf16(ea, pb, zf, 0, 0, 0);
  }
#pragma unroll
  for (int nt=0; nt<2; nt++)
#pragma unroll
    for (int i=0; i<4; i++){
      int h = lg*4 + i;
      emt[h*32 + nt*16 + l15] = f2bf(o[nt][i]);
    }
}

// =====================================================================
// ===== Fallback (R0 fused kernel, verbatim) — used only if ws too small =====
#define LDS_X   0u
#define LDS_V   50176u
#define LDS_QK  100352u
#define LDS_RPB 150528u
#define LDS_PW  50176u
#define LDS_EM  0u
#define LDS_TOTAL 155936

__device__ __forceinline__ void gemm_strip(const unsigned char* ldsp, unsigned abase,
    const u16* __restrict__ W, int wrow0, int l15, int lg, f32x4 acc[4][4]){
  for (int kk = 0; kk < 16; kk++){
    short8 bq[4];
#pragma unroll
    for (int nt = 0; nt < 4; nt++){
      const u16* p = W + (size_t)(wrow0 + nt*16 + l15) * 512 + kk*32 + lg*8;
      bq[nt] = *(const short8*)p;
    }
    short8 aq[4];
#pragma unroll
    for (int mt = 0; mt < 4; mt++){
      int r = mt*16 + l15; if (r > 48) r = 48;
      aq[mt] = *(const short8*)(ldsp + swz(abase, r, 1024u, (unsigned)(kk*64 + lg*16)));
    }
#pragma unroll
    for (int mt = 0; mt < 4; mt++)
#pragma unroll
      for (int nt = 0; nt < 4; nt++)
        acc[mt][nt] = __builtin_amdgcn_mfma_f32_16x16x32_bf16(aq[mt], bq[nt], acc[mt][nt], 0, 0, 0);
  }
}

__global__ void conv_w4(const float* __restrict__ a, const float* __restrict__ b,
                        const float* __restrict__ c, const float* __restrict__ d,
                        u16* __restrict__ o){
  int i = blockIdx.x * 256 + threadIdx.x;
  if (i < 524288)        o[i] = f2bf(a[i]);
  else if (i < 786432)   o[i] = f2bf(b[i - 524288]);
  else if (i < 1310720)  o[i] = f2bf(c[i - 786432]);
  else                   o[i] = f2bf(d[i - 1310720]);
}

__launch_bounds__(512, 2)
__global__ void wa_main(
    const float* __restrict__ x, const float* __restrict__ qk_b,
    const float* __restrict__ rev_v_b, const float* __restrict__ proj_b,
    const float* __restrict__ rpb,
    const u16* __restrict__ Wqk, const u16* __restrict__ Wv,
    const u16* __restrict__ Wwg, const u16* __restrict__ Wproj,
    float* __restrict__ out){
  __shared__ __align__(16) unsigned char ldsp[LDS_TOTAL];
  const int tid  = threadIdx.x;
  const int wave = tid >> 6, lane = tid & 63, l15 = lane & 15, lg = lane >> 4;
  const int b = blockIdx.x;
  const float* xb = x + (size_t)b * 49 * 512;
  const f32x4 zf = {0.f, 0.f, 0.f, 0.f};
  for (int i = tid; i < 169*16; i += 512)
    *(u16*)(ldsp + LDS_RPB + i*2) = f2bf(rpb[i]);
  for (int ch = tid; ch < 49*64; ch += 512){
    int r = ch >> 6, c8 = ch & 63;
    const f32x4* s = (const f32x4*)(xb + r*512 + c8*8);
    f32x4 lo = s[0], hi = s[1];
    short8 v;
    v[0]=f2bf(lo[0]); v[1]=f2bf(lo[1]); v[2]=f2bf(lo[2]); v[3]=f2bf(lo[3]);
    v[4]=f2bf(hi[0]); v[5]=f2bf(hi[1]); v[6]=f2bf(hi[2]); v[7]=f2bf(hi[3]);
    *(short8*)(ldsp + swz(LDS_X, r, 1024u, (unsigned)(c8*16))) = v;
  }
  __syncthreads();
  {
    f32x4 acc[4][4];
#pragma unroll
    for (int mt=0; mt<4; mt++)
#pragma unroll
      for (int nt=0; nt<4; nt++) acc[mt][nt] = zf;
    gemm_strip(ldsp, LDS_X, Wv, wave*64, l15, lg, acc);
#pragma unroll
    for (int nt=0; nt<4; nt++){
      int ch = wave*64 + nt*16 + l15;
      float bias = rev_v_b[ch];
#pragma unroll
      for (int mt=0; mt<4; mt++)
#pragma unroll
        for (int i=0; i<4; i++){
          int r = mt*16 + lg*4 + i;
          if (r < 49)
            *(u16*)(ldsp + swz(LDS_V, r, 1024u, (unsigned)(ch*2))) = f2bf(acc[mt][nt][i] + bias);
        }
    }
  }
  auto qk_pass = [&](int p){
    f32x4 acc[4][4];
#pragma unroll
    for (int mt=0; mt<4; mt++)
#pragma unroll
      for (int nt=0; nt<4; nt++) acc[mt][nt] = zf;
    int wrow0 = (wave < 4) ? (p*256 + wave*64) : (512 + p*256 + (wave-4)*64);
    gemm_strip(ldsp, LDS_X, Wqk, wrow0, l15, lg, acc);
#pragma unroll
    for (int nt=0; nt<4; nt++){
      int ch  = wrow0 + nt*16 + l15;
      int col = wave*64 + nt*16 + l15;
      float bias = qk_b[ch];
#pragma unroll
      for (int mt=0; mt<4; mt++)
#pragma unroll
        for (int i=0; i<4; i++){
          int r = mt*16 + lg*4 + i;
          if (r < 49)
            *(u16*)(ldsp + swz(LDS_QK, r, 1024u, (unsigned)(col*2))) = f2bf(acc[mt][nt][i] + bias);
        }
    }
  };
  auto attn_pass = [&](int p, f32x4 (&em)[4][2]){
    const int h = p*8 + wave;
    f32x4 s[4][4];
#pragma unroll
    for (int mt=0; mt<4; mt++)
#pragma unroll
      for (int nt=0; nt<4; nt++) s[mt][nt] = zf;
    short8 aq[4], bq[4];
#pragma unroll
    for (int mt=0; mt<4; mt++){
      int r = mt*16 + l15; if (r > 48) r = 48;
      aq[mt] = *(const short8*)(ldsp + swz(LDS_QK, r, 1024u, (unsigned)(wave*64 + lg*16)));
    }
#pragma unroll
    for (int nt=0; nt<4; nt++){
      int kt = nt*16 + l15; if (kt > 48) kt = 48;
      bq[nt] = *(const short8*)(ldsp + swz(LDS_QK, kt, 1024u, (unsigned)(512 + wave*64 + lg*16)));
    }
#pragma unroll
    for (int mt=0; mt<4; mt++)
#pragma unroll
      for (int nt=0; nt<4; nt++)
        s[mt][nt] = __builtin_amdgcn_mfma_f32_16x16x32_bf16(aq[mt], bq[nt], s[mt][nt], 0, 0, 0);
#pragma unroll
    for (int mt=0; mt<4; mt++)
#pragma unroll
      for (int nt=0; nt<4; nt++)
#pragma unroll
        for (int i=0; i<4; i++){
          int q  = mt*16 + lg*4 + i;
          int kt = nt*16 + l15;
          float v = s[mt][nt][i] * SCALE_F;
          if (kt < 49){
            int qc = (q > 48) ? 48 : q;
            int qi = qc / 7, qj = qc - qi*7;
            int ki = kt / 7, kj = kt - ki*7;
            int idx = (qi - ki + 6)*13 + (qj - kj + 6);
            v += bf2f(*(const u16*)(ldsp + LDS_RPB + (idx*16 + h)*2));
          } else v = -1e30f;
          s[mt][nt][i] = v;
        }
#pragma unroll
    for (int mt=0; mt<4; mt++)
#pragma unroll
      for (int i=0; i<4; i++){
        float m = fmaxf(fmaxf(s[mt][0][i], s[mt][1][i]), fmaxf(s[mt][2][i], s[mt][3][i]));
        m = fmaxf(m, __shfl_xor(m, 1)); m = fmaxf(m, __shfl_xor(m, 2));
        m = fmaxf(m, __shfl_xor(m, 4)); m = fmaxf(m, __shfl_xor(m, 8));
        float sum = 0.f;
#pragma unroll
        for (int nt=0; nt<4; nt++){ float e = __expf(s[mt][nt][i] - m); s[mt][nt][i] = e; sum += e; }
        sum += __shfl_xor(sum, 1); sum += __shfl_xor(sum, 2);
        sum += __shfl_xor(sum, 4); sum += __shfl_xor(sum, 8);
        float inv = 1.0f / sum;
#pragma unroll
        for (int nt=0; nt<4; nt++) s[mt][nt][i] *= inv;
      }
    __syncthreads();
    const unsigned ptb = LDS_QK + (unsigned)wave * 6272u;
#pragma unroll
    for (int mt=0; mt<4; mt++)
#pragma unroll
      for (int nt=0; nt<4; nt++)
#pragma unroll
        for (int i=0; i<4; i++){
          int q  = mt*16 + lg*4 + i;
          int kt = nt*16 + l15;
          if (kt < 49){
            u16 val = (q < 49) ? f2bf(s[mt][nt][i]) : (u16)0;
            *(u16*)(ldsp + ptb + (unsigned)kt*128u + (((unsigned)(q*2)) ^ (((unsigned)kt & 7u) << 4))) = val;
          }
        }
#pragma unroll
    for (int kk=0; kk<2; kk++){
      short8 pa[4];
#pragma unroll
      for (int mt=0; mt<4; mt++){
        int r = mt*16 + l15; if (r > 48) r = 48;
        pa[mt] = *(const short8*)(ldsp + ptb + (unsigned)r*128u + (((unsigned)(kk*64 + lg*16)) ^ (((unsigned)r & 7u) << 4)));
      }
      short8 vb[2];
#pragma unroll
      for (int nt=0; nt<2; nt++){
        int ch = h*32 + nt*16 + l15;
#pragma unroll
        for (int j=0; j<8; j++){
          int kt = kk*32 + lg*8 + j; if (kt > 48) kt = 48;
          vb[nt][j] = *(const short*)(ldsp + swz(LDS_V, kt, 1024u, (unsigned)(ch*2)));
        }
      }
#pragma unroll
      for (int mt=0; mt<4; mt++)
#pragma unroll
        for (int nt=0; nt<2; nt++)
          em[mt][nt] = __builtin_amdgcn_mfma_f32_16x16x32_bf16(pa[mt], vb[nt], em[mt][nt], 0, 0, 0);
    }
  };
  f32x4 em0[4][2], em1[4][2];
#pragma unroll
  for (int mt=0; mt<4; mt++)
#pragma unroll
    for (int nt=0; nt<2; nt++){ em0[mt][nt] = zf; em1[mt][nt] = zf; }
  qk_pass(0);
  __syncthreads();
  attn_pass(0, em0);
  __syncthreads();
  qk_pass(1);
  __syncthreads();
  attn_pass(1, em1);
  __syncthreads();
  for (int nh = 0; nh < 2; nh++){
    f32x4 acc[4][4];
#pragma unroll
    for (int mt=0; mt<4; mt++)
#pragma unroll
      for (int nt=0; nt<4; nt++) acc[mt][nt] = zf;
    int n0 = nh*512 + wave*64;
    gemm_strip(ldsp, LDS_X, Wwg, n0, l15, lg, acc);
#pragma unroll
    for (int nt=0; nt<4; nt++){
      int n  = n0 + nt*16 + l15;
      int pc = (n & 31)*32 + (n >> 5);
      unsigned cb = ((unsigned)(pc*2)) ^ (((unsigned)n & 7u) << 4);
#pragma unroll
      for (int mt=0; mt<4; mt++)
#pragma unroll
        for (int i=0; i<4; i++){
          int r = mt*16 + lg*4 + i;
          if (r < 49)
            *(u16*)(ldsp + LDS_PW + (unsigned)r*2048u + cb) = f2bf(acc[mt][nt][i]);
        }
    }
  }
  __syncthreads();
  auto em_store = [&](f32x4 (&em)[4][2], int h){
#pragma unroll
    for (int mt=0; mt<4; mt++)
#pragma unroll
      for (int nt=0; nt<2; nt++)
#pragma unroll
        for (int i=0; i<4; i++){
          int q = mt*16 + lg*4 + i;
          if (q < 49){
            int ch = h*32 + nt*16 + l15;
            *(u16*)(ldsp + swz(LDS_EM, q, 1024u, (unsigned)(ch*2))) = f2bf(em[mt][nt][i]);
          }
        }
  };
  em_store(em0, wave);
  em_store(em1, 8 + wave);
  __syncthreads();
  for (int t = wave; t < 49; t += 8){
    short8 ea = *(const short8*)(ldsp + swz(LDS_EM, t, 1024u, (unsigned)(l15*64 + lg*16)));
    f32x4 o[2];
#pragma unroll
    for (int nt=0; nt<2; nt++){
      int f = nt*16 + l15;
      short8 pb = *(const short8*)(ldsp + LDS_PW + (unsigned)t*2048u +
                    (((unsigned)((f*32 + lg*8)*2)) ^ (((unsigned)f & 7u) << 4)));
      o[nt] = __builtin_amdgcn_mfma_f32_16x16x32_bf16(ea, pb, zf, 0, 0, 0);
    }
#pragma unroll
    for (int nt=0; nt<2; nt++)
#pragma unroll
      for (int i=0; i<4; i++){
        int h2 = lg*4 + i;
        int ch = h2*32 + nt*16 + l15;
        *(u16*)(ldsp + swz(LDS_EM, t, 1024u, (unsigned)(ch*2))) = f2bf(o[nt][i]);
      }
  }
  __syncthreads();
  {
    f32x4 acc[4][4];
#pragma unroll
    for (int mt=0; mt<4; mt++)
#pragma unroll
      for (int nt=0; nt<4; nt++) acc[mt][nt] = zf;
    gemm_strip(ldsp, LDS_EM, Wproj, wave*64, l15, lg, acc);
    float* ob = out + (size_t)b * 49 * 512;
#pragma unroll
    for (int nt=0; nt<4; nt++){
      int n = wave*64 + nt*16 + l15;
      float bias = proj_b[n];
#pragma unroll
      for (int mt=0; mt<4; mt++)
#pragma unroll
        for (int i=0; i<4; i++){
          int r = mt*16 + lg*4 + i;
          if (r < 49) ob[r*512 + n] = acc[mt][nt][i] + bias;
        }
    }
  }
}

// =====================================================================
extern "C" void kernel_launch(void* const* d_in, const int* in_sizes, int n_in,
                              void* d_out, int out_size, void* d_ws, size_t ws_size,
                              hipStream_t stream){
  const float* x       = (const float*)d_in[0];
  const float* qk_w    = (const float*)d_in[1];
  const float* qk_b    = (const float*)d_in[2];
  const float* rev_v_w = (const float*)d_in[3];
  const float* rev_v_b = (const float*)d_in[4];
  const float* wg_w    = (const float*)d_in[5];
  const float* proj_w  = (const float*)d_in[6];
  const float* proj_b  = (const float*)d_in[7];
  const float* rpb     = (const float*)d_in[8];
  u16* ws = (u16*)d_ws;

  // ws element layout: Wcat[2560][512] | Wproj[512][512] | xb[100352][512] | qkvpw | em
  const unsigned long long BASE = 105906176ULL;  // bytes up to chunk regions
  int C = 0;
  for (int cand : {2048, 1024, 512, 256, 128}){
    if (BASE + (unsigned long long)cand * 301056ULL <= ws_size){ C = cand; break; }
  }
  if (C == 0){
    // fallback: original fused kernel (needs only 3.1MB ws)
    conv_w4<<<6144, 256, 0, stream>>>(qk_w, rev_v_w, wg_w, proj_w, ws);
    wa_main<<<2048, 512, 0, stream>>>(x, qk_b, rev_v_b, proj_b, rpb,
        ws, ws + 524288, ws + 786432, ws + 1310720, (float*)d_out);
    return;
  }

  u16* Wcat  = ws;                    // rows: qk 0..1023 | v 1024..1535 | wg 1536..2559
  u16* Wproj = ws + 1310720;
  u16* xb    = ws + 1572864;
  u16* qkvpw = ws + 52953088ULL;
  u16* em    = qkvpw + (size_t)C * 49 * 2560;

  convk<<<25856, 256, 0, stream>>>(x, qk_w, rev_v_w, wg_w, proj_w, ws);

  const int nch = 2048 / C;
  const int mt128 = C * 49 / 128;
  for (int ch = 0; ch < nch; ch++){
    size_t t0 = (size_t)ch * C * 49;
    gemm128<20, 0><<<mt128 * 20, 256, 0, stream>>>(xb + t0*512, 512, Wcat,
        qk_b, rev_v_b, qkvpw, 2560);
    attn_k<<<C, 512, 0, stream>>>(qkvpw, rpb, em);
    hyper_k<<<C * 49 / 8, 512, 0, stream>>>(qkvpw, em);
    gemm128<4, 1><<<mt128 * 4, 256, 0, stream>>>(em, 512, Wproj,
        proj_b, (const float*)nullptr, (float*)d_out + t0*512, 512);
  }
}

// Round 4
// 690.967 us; speedup vs baseline: 1.5730x; 1.1761x over previous
//
#include <hip/hip_runtime.h>
#include <hip/hip_bf16.h>
#include <stdint.h>

typedef __attribute__((ext_vector_type(8))) short short8;
typedef __attribute__((ext_vector_type(4))) float f32x4;
typedef unsigned short u16;

#define SCALE_F 0.17677669529663687f

__device__ __forceinline__ u16 f2bf(float f){
  union { float f; unsigned u; } x; x.f = f;
  unsigned r = x.u + 0x7fffu + ((x.u >> 16) & 1u);
  return (u16)(r >> 16);
}
__device__ __forceinline__ float bf2f(u16 u){
  union { float f; unsigned u; } x; x.u = ((unsigned)u) << 16; return x.f;
}
// XOR-swizzled LDS byte address within a row (rowb bytes/row)
__device__ __forceinline__ unsigned swz(unsigned base, int row, unsigned rowb, unsigned colb){
  return base + (unsigned)row * rowb + (colb ^ (((unsigned)row & 7u) << 4));
}
// async global->LDS 16B
__device__ __forceinline__ void gll16(const void* g, void* l){
  __builtin_amdgcn_global_load_lds(
    (const __attribute__((address_space(1))) unsigned int*)(unsigned long long)(size_t)g,
    (__attribute__((address_space(3))) unsigned int*)(unsigned int)(size_t)l,
    16, 0, 0);
}

// =====================================================================
// conv: W (qk|v|wg|proj -> Wcat layout) + x, fp32 -> bf16 into ws
__global__ void convk(const float* __restrict__ x,
                      const float* __restrict__ qk_w, const float* __restrict__ rev_v_w,
                      const float* __restrict__ wg_w, const float* __restrict__ proj_w,
                      u16* __restrict__ ws){
  long long i8 = ((long long)blockIdx.x * 256 + threadIdx.x) * 8;
  const float* s;
  if      (i8 <  524288) s = qk_w   + i8;
  else if (i8 <  786432) s = rev_v_w + (i8 - 524288);
  else if (i8 < 1310720) s = wg_w   + (i8 - 786432);
  else if (i8 < 1572864) s = proj_w + (i8 - 1310720);
  else                   s = x      + (i8 - 1572864);
  f32x4 lo = *(const f32x4*)s, hi = *(const f32x4*)(s + 4);
  short8 v;
  v[0]=f2bf(lo[0]); v[1]=f2bf(lo[1]); v[2]=f2bf(lo[2]); v[3]=f2bf(lo[3]);
  v[4]=f2bf(hi[0]); v[5]=f2bf(hi[1]); v[6]=f2bf(hi[2]); v[7]=f2bf(hi[3]);
  *(short8*)(ws + i8) = v;
}

// =====================================================================
// 128x128-tile GEMM (m97 structure): C[M x NT*128] = A[M x 512] @ B^T, B=[NT*128][512]
template<int NT, int F32OUT>
__global__ __launch_bounds__(256, 2)
void gemm128(const u16* __restrict__ A, int lda,
             const u16* __restrict__ B,
             const float* __restrict__ b0, const float* __restrict__ b1,
             void* __restrict__ Cg, int ldc){
  __shared__ __align__(16) unsigned char sm[32768];
  const int tid = threadIdx.x, wave = tid >> 6, lane = tid & 63;
  const int l15 = lane & 15, lg = lane >> 4;
  const int nwg = gridDim.x, bidr = blockIdx.x;
  const int q8 = nwg >> 3, r8 = nwg & 7, xc = bidr & 7, oo = bidr >> 3;
  const int wg = (xc < r8 ? xc * (q8 + 1) : r8 * (q8 + 1) + (xc - r8) * q8) + oo;
  const int bm = wg / NT, bn = wg % NT;
  const int wm = wave >> 1, wn = wave & 1;
  const f32x4 zf = {0.f, 0.f, 0.f, 0.f};
  f32x4 acc[4][4];
#pragma unroll
  for (int mt=0; mt<4; mt++)
#pragma unroll
    for (int nt=0; nt<4; nt++) acc[mt][nt] = zf;

  const u16* Ab = A + (size_t)bm * 128 * lda;
  const u16* Bb = B + (size_t)bn * 128 * 512;

  for (int ks = 0; ks < 8; ks++){
#pragma unroll
    for (int it = 0; it < 4; it++){
      int c = (wave*4 + it)*64 + lane;
      int r = c >> 3, cc = c & 7;
      int sc = cc ^ (r & 7);
      gll16(Ab + (size_t)r*lda + ks*64 + sc*8, sm + (unsigned)(wave*4 + it)*1024u);
      gll16(Bb + (size_t)r*512 + ks*64 + sc*8, sm + 16384u + (unsigned)(wave*4 + it)*1024u);
    }
    __syncthreads();
#pragma unroll
    for (int kk = 0; kk < 2; kk++){
      short8 aq[4], bq[4];
#pragma unroll
      for (int mt=0; mt<4; mt++){
        int r = wm*64 + mt*16 + l15;
        aq[mt] = *(const short8*)(sm + (unsigned)r*128u + (((unsigned)(kk*64 + lg*16)) ^ (((unsigned)r & 7u) << 4)));
      }
#pragma unroll
      for (int nt=0; nt<4; nt++){
        int r = wn*64 + nt*16 + l15;
        bq[nt] = *(const short8*)(sm + 16384u + (unsigned)r*128u + (((unsigned)(kk*64 + lg*16)) ^ (((unsigned)r & 7u) << 4)));
      }
#pragma unroll
      for (int mt=0; mt<4; mt++)
#pragma unroll
        for (int nt=0; nt<4; nt++)
          acc[mt][nt] = __builtin_amdgcn_mfma_f32_16x16x32_bf16(aq[mt], bq[nt], acc[mt][nt], 0, 0, 0);
    }
    __syncthreads();
  }

  float bia[4];
#pragma unroll
  for (int nt=0; nt<4; nt++){
    int n = bn*128 + wn*64 + nt*16 + l15;
    if (F32OUT) bia[nt] = b0[n];
    else        bia[nt] = (n < 1024) ? b0[n] : (n < 1536 ? b1[n - 1024] : 0.f);
  }

  if (!F32OUT){
#pragma unroll
    for (int mt=0; mt<4; mt++)
#pragma unroll
      for (int nt=0; nt<4; nt++)
#pragma unroll
        for (int i=0; i<4; i++){
          int row = wm*64 + mt*16 + lg*4 + i;
          unsigned colb = (unsigned)((wn*64 + nt*16 + l15) * 2);
          *(u16*)(sm + (unsigned)row*256u + (colb ^ (((unsigned)row & 7u) << 4))) = f2bf(acc[mt][nt][i] + bia[nt]);
        }
    __syncthreads();
    u16* Co = (u16*)Cg;
#pragma unroll
    for (int it=0; it<8; it++){
      int c = it*256 + tid;
      int r = c >> 4, cc = c & 15;
      short8 v = *(const short8*)(sm + (unsigned)r*256u + (((unsigned)(cc*16)) ^ (((unsigned)r & 7u) << 4)));
      *(short8*)(Co + (size_t)(bm*128 + r)*ldc + bn*128 + cc*8) = v;
    }
  } else {
    float* Co = (float*)Cg;
#pragma unroll
    for (int half=0; half<2; half++){
      if (wm == half){
#pragma unroll
        for (int mt=0; mt<4; mt++)
#pragma unroll
          for (int nt=0; nt<4; nt++)
#pragma unroll
            for (int i=0; i<4; i++){
              int row = mt*16 + lg*4 + i;
              unsigned colb = (unsigned)((wn*64 + nt*16 + l15) * 4);
              *(float*)(sm + (unsigned)row*512u + (colb ^ (((unsigned)row & 7u) << 4))) = acc[mt][nt][i] + bia[nt];
            }
      }
      __syncthreads();
#pragma unroll
      for (int it=0; it<8; it++){
        int c = it*256 + tid;
        int r = c >> 5, cc = c & 31;
        f32x4 v = *(const f32x4*)(sm + (unsigned)r*512u + (((unsigned)(cc*16)) ^ (((unsigned)r & 7u) << 4)));
        *(f32x4*)(Co + (size_t)(bm*128 + half*64 + r)*ldc + bn*128 + cc*4) = v;
      }
      __syncthreads();
    }
  }
}

// =====================================================================
// Fused attention + hypernet per window.
// qkvpw rows [t][2560] = q|k|v|pw. Output o1[t][512] bf16 (pre-proj).
// LDS: V 50176 (later reused for em/out1) | PT 8x6272 | RPB 5408 = 105760 B.
__global__ __launch_bounds__(512, 2)
void attn_fused(const u16* __restrict__ qkv, const float* __restrict__ rpb,
                u16* __restrict__ o1){
  __shared__ __align__(16) unsigned char lds[105760];
  const unsigned L_V = 0u, L_PT = 50176u, L_RPB = 100352u;
  const int tid = threadIdx.x, wave = tid >> 6, lane = tid & 63;
  const int l15 = lane & 15, lg = lane >> 4;
  const size_t wb = (size_t)blockIdx.x * 49;
  const u16* base = qkv + wb * 2560;
  unsigned char* ptb = lds + L_PT + (unsigned)wave * 6272u;
  const f32x4 zf = {0.f, 0.f, 0.f, 0.f};

  // stage rpb (bf16) + V (swizzled rows)
  for (int i = tid; i < 2704; i += 512)
    *(u16*)(lds + L_RPB + i*2) = f2bf(rpb[i]);
  for (int c = tid; c < 49*64; c += 512){
    int r = c >> 6, c8 = c & 63;
    short8 v = *(const short8*)(base + (size_t)r*2560 + 1024 + c8*8);
    *(short8*)(lds + swz(L_V, r, 1024u, (unsigned)(c8*16))) = v;
  }
  __syncthreads();

  auto attn_pass = [&](int hp, f32x4 (&em)[4][2]){
    const int h = wave + hp*8;
    short8 aq[4], bq[4];
#pragma unroll
    for (int mt=0; mt<4; mt++){
      int r = mt*16 + l15; if (r > 48) r = 48;
      aq[mt] = *(const short8*)(base + (size_t)r*2560 + h*32 + lg*8);
    }
#pragma unroll
    for (int nt=0; nt<4; nt++){
      int kt = nt*16 + l15; if (kt > 48) kt = 48;
      bq[nt] = *(const short8*)(base + (size_t)kt*2560 + 512 + h*32 + lg*8);
    }
    f32x4 s[4][4];
#pragma unroll
    for (int mt=0; mt<4; mt++)
#pragma unroll
      for (int nt=0; nt<4; nt++) s[mt][nt] = zf;
#pragma unroll
    for (int mt=0; mt<4; mt++)
#pragma unroll
      for (int nt=0; nt<4; nt++)
        s[mt][nt] = __builtin_amdgcn_mfma_f32_16x16x32_bf16(aq[mt], bq[nt], s[mt][nt], 0, 0, 0);
    // scale + rel-pos bias (LDS) + mask padded keys
#pragma unroll
    for (int mt=0; mt<4; mt++)
#pragma unroll
      for (int nt=0; nt<4; nt++)
#pragma unroll
        for (int i=0; i<4; i++){
          int q  = mt*16 + lg*4 + i;
          int kt = nt*16 + l15;
          float v = s[mt][nt][i] * SCALE_F;
          if (kt < 49){
            int qc = (q > 48) ? 48 : q;
            int qi = qc / 7, qj = qc - qi*7;
            int ki = kt / 7, kj = kt - ki*7;
            int idx = (qi - ki + 6)*13 + (qj - kj + 6);
            v += bf2f(*(const u16*)(lds + L_RPB + (idx*16 + h)*2));
          } else v = -1e30f;
          s[mt][nt][i] = v;
        }
    // wave-parallel softmax over key dim
#pragma unroll
    for (int mt=0; mt<4; mt++)
#pragma unroll
      for (int i=0; i<4; i++){
        float m = fmaxf(fmaxf(s[mt][0][i], s[mt][1][i]), fmaxf(s[mt][2][i], s[mt][3][i]));
        m = fmaxf(m, __shfl_xor(m, 1)); m = fmaxf(m, __shfl_xor(m, 2));
        m = fmaxf(m, __shfl_xor(m, 4)); m = fmaxf(m, __shfl_xor(m, 8));
        float sum = 0.f;
#pragma unroll
        for (int nt=0; nt<4; nt++){ float e = __expf(s[mt][nt][i] - m); s[mt][nt][i] = e; sum += e; }
        sum += __shfl_xor(sum, 1); sum += __shfl_xor(sum, 2);
        sum += __shfl_xor(sum, 4); sum += __shfl_xor(sum, 8);
        float inv = 1.0f / sum;
#pragma unroll
        for (int nt=0; nt<4; nt++) s[mt][nt][i] *= inv;
      }
    // store P transposed (PT[kt][q]); zero padded q
#pragma unroll
    for (int mt=0; mt<4; mt++)
#pragma unroll
      for (int nt=0; nt<4; nt++)
#pragma unroll
        for (int i=0; i<4; i++){
          int q  = mt*16 + lg*4 + i;
          int kt = nt*16 + l15;
          if (kt < 49){
            u16 val = (q < 49) ? f2bf(s[mt][nt][i]) : (u16)0;
            *(u16*)(ptb + (unsigned)kt*128u + (((unsigned)(q*2)) ^ (((unsigned)kt & 7u) << 4))) = val;
          }
        }
    // em += PT-as-A @ V_head (V from LDS)
#pragma unroll
    for (int kk=0; kk<2; kk++){
      short8 pa[4];
#pragma unroll
      for (int mt=0; mt<4; mt++){
        int r = mt*16 + l15; if (r > 48) r = 48;
        pa[mt] = *(const short8*)(ptb + (unsigned)r*128u + (((unsigned)(kk*64 + lg*16)) ^ (((unsigned)r & 7u) << 4)));
      }
      short8 vb[2];
#pragma unroll
      for (int nt=0; nt<2; nt++){
        int ch = h*32 + nt*16 + l15;
#pragma unroll
        for (int j=0; j<8; j++){
          int kt = kk*32 + lg*8 + j; if (kt > 48) kt = 48;
          vb[nt][j] = *(const short*)(lds + swz(L_V, kt, 1024u, (unsigned)(ch*2)));
        }
      }
#pragma unroll
      for (int mt=0; mt<4; mt++)
#pragma unroll
        for (int nt=0; nt<2; nt++)
          em[mt][nt] = __builtin_amdgcn_mfma_f32_16x16x32_bf16(pa[mt], vb[nt], em[mt][nt], 0, 0, 0);
    }
  };

  f32x4 em0[4][2], em1[4][2];
#pragma unroll
  for (int mt=0; mt<4; mt++)
#pragma unroll
    for (int nt=0; nt<2; nt++){ em0[mt][nt] = zf; em1[mt][nt] = zf; }
  attn_pass(0, em0);
  attn_pass(1, em1);
  __syncthreads();   // all V reads done -> reuse L_V for em

  // em -> LDS [49][512] (ch = h*32+e)
  auto em_store = [&](f32x4 (&em)[4][2], int h){
#pragma unroll
    for (int mt=0; mt<4; mt++)
#pragma unroll
      for (int nt=0; nt<2; nt++)
#pragma unroll
        for (int i=0; i<4; i++){
          int q = mt*16 + lg*4 + i;
          if (q < 49){
            int ch = h*32 + nt*16 + l15;
            *(u16*)(lds + swz(L_V, q, 1024u, (unsigned)(ch*2))) = f2bf(em[mt][nt][i]);
          }
        }
  };
  em_store(em0, wave);
  em_store(em1, 8 + wave);
  __syncthreads();

  // hypernet per token; pw staged permuted ([f][e]) into wave's PT scratch.
  // Swizzle uses (f&3)<<4 ONLY: row is 64 B (e*2 spans bits 1..5), so the XOR
  // constant must stay within bits 4..5 to remain bijective per-row.
  // (R2 bug: (f&7)<<4 set bit 6 -> rows f and f^... collided across rows.)
  for (int t = wave; t < 49; t += 8){
    const u16* pwt = base + (size_t)t*2560 + 1536;
#pragma unroll
    for (int rd = 0; rd < 2; rd++){
      int i8 = (rd*64 + lane)*8;
      short8 v = *(const short8*)(pwt + i8);
      int e = i8 >> 5, f0 = i8 & 31;
#pragma unroll
      for (int jj = 0; jj < 8; jj++){
        int f = f0 + jj;
        *(u16*)(ptb + (unsigned)f*64u + (((unsigned)(e*2)) ^ (((unsigned)f & 3u) << 4))) = (u16)v[jj];
      }
    }
    short8 ea = *(const short8*)(lds + swz(L_V, t, 1024u, (unsigned)(l15*64 + lg*16)));
    f32x4 o[2];
#pragma unroll
    for (int nt=0; nt<2; nt++){
      int f = nt*16 + l15;
      short8 pb = *(const short8*)(ptb + (unsigned)f*64u + (((unsigned)(lg*16)) ^ (((unsigned)f & 3u) << 4)));
      o[nt] = __builtin_amdgcn_mfma_f32_16x16x32_bf16(ea, pb, zf, 0, 0, 0);
    }
#pragma unroll
    for (int nt=0; nt<2; nt++)
#pragma unroll
      for (int i=0; i<4; i++){
        int ch = (lg*4 + i)*32 + nt*16 + l15;
        *(u16*)(lds + swz(L_V, t, 1024u, (unsigned)(ch*2))) = f2bf(o[nt][i]);
      }
  }
  __syncthreads();

  // flush out1 rows coalesced
  u16* ob = o1 + wb * 512;
  for (int c = tid; c < 49*64; c += 512){
    int r = c >> 6, c8 = c & 63;
    short8 v = *(const short8*)(lds + swz(L_V, r, 1024u, (unsigned)(c8*16)));
    *(short8*)(ob + (size_t)r*512 + c8*8) = v;
  }
}

// =====================================================================
// ===== Fallback (R0 fused kernel) — used only if ws too small =====
#define LDS_X   0u
#define LDS_V   50176u
#define LDS_QK  100352u
#define LDS_RPB 150528u
#define LDS_PW  50176u
#define LDS_EM  0u
#define LDS_TOTAL 155936

__device__ __forceinline__ void gemm_strip(const unsigned char* ldsp, unsigned abase,
    const u16* __restrict__ W, int wrow0, int l15, int lg, f32x4 acc[4][4]){
  for (int kk = 0; kk < 16; kk++){
    short8 bq[4];
#pragma unroll
    for (int nt = 0; nt < 4; nt++){
      const u16* p = W + (size_t)(wrow0 + nt*16 + l15) * 512 + kk*32 + lg*8;
      bq[nt] = *(const short8*)p;
    }
    short8 aq[4];
#pragma unroll
    for (int mt = 0; mt < 4; mt++){
      int r = mt*16 + l15; if (r > 48) r = 48;
      aq[mt] = *(const short8*)(ldsp + swz(abase, r, 1024u, (unsigned)(kk*64 + lg*16)));
    }
#pragma unroll
    for (int mt = 0; mt < 4; mt++)
#pragma unroll
      for (int nt = 0; nt < 4; nt++)
        acc[mt][nt] = __builtin_amdgcn_mfma_f32_16x16x32_bf16(aq[mt], bq[nt], acc[mt][nt], 0, 0, 0);
  }
}

__global__ void conv_w4(const float* __restrict__ a, const float* __restrict__ b,
                        const float* __restrict__ c, const float* __restrict__ d,
                        u16* __restrict__ o){
  int i = blockIdx.x * 256 + threadIdx.x;
  if (i < 524288)        o[i] = f2bf(a[i]);
  else if (i < 786432)   o[i] = f2bf(b[i - 524288]);
  else if (i < 1310720)  o[i] = f2bf(c[i - 786432]);
  else                   o[i] = f2bf(d[i - 1310720]);
}

__launch_bounds__(512, 2)
__global__ void wa_main(
    const float* __restrict__ x, const float* __restrict__ qk_b,
    const float* __restrict__ rev_v_b, const float* __restrict__ proj_b,
    const float* __restrict__ rpb,
    const u16* __restrict__ Wqk, const u16* __restrict__ Wv,
    const u16* __restrict__ Wwg, const u16* __restrict__ Wproj,
    float* __restrict__ out){
  __shared__ __align__(16) unsigned char ldsp[LDS_TOTAL];
  const int tid  = threadIdx.x;
  const int wave = tid >> 6, lane = tid & 63, l15 = lane & 15, lg = lane >> 4;
  const int b = blockIdx.x;
  const float* xb = x + (size_t)b * 49 * 512;
  const f32x4 zf = {0.f, 0.f, 0.f, 0.f};
  for (int i = tid; i < 169*16; i += 512)
    *(u16*)(ldsp + LDS_RPB + i*2) = f2bf(rpb[i]);
  for (int ch = tid; ch < 49*64; ch += 512){
    int r = ch >> 6, c8 = ch & 63;
    const f32x4* s = (const f32x4*)(xb + r*512 + c8*8);
    f32x4 lo = s[0], hi = s[1];
    short8 v;
    v[0]=f2bf(lo[0]); v[1]=f2bf(lo[1]); v[2]=f2bf(lo[2]); v[3]=f2bf(lo[3]);
    v[4]=f2bf(hi[0]); v[5]=f2bf(hi[1]); v[6]=f2bf(hi[2]); v[7]=f2bf(hi[3]);
    *(short8*)(ldsp + swz(LDS_X, r, 1024u, (unsigned)(c8*16))) = v;
  }
  __syncthreads();
  {
    f32x4 acc[4][4];
#pragma unroll
    for (int mt=0; mt<4; mt++)
#pragma unroll
      for (int nt=0; nt<4; nt++) acc[mt][nt] = zf;
    gemm_strip(ldsp, LDS_X, Wv, wave*64, l15, lg, acc);
#pragma unroll
    for (int nt=0; nt<4; nt++){
      int ch = wave*64 + nt*16 + l15;
      float bias = rev_v_b[ch];
#pragma unroll
      for (int mt=0; mt<4; mt++)
#pragma unroll
        for (int i=0; i<4; i++){
          int r = mt*16 + lg*4 + i;
          if (r < 49)
            *(u16*)(ldsp + swz(LDS_V, r, 1024u, (unsigned)(ch*2))) = f2bf(acc[mt][nt][i] + bias);
        }
    }
  }
  auto qk_pass = [&](int p){
    f32x4 acc[4][4];
#pragma unroll
    for (int mt=0; mt<4; mt++)
#pragma unroll
      for (int nt=0; nt<4; nt++) acc[mt][nt] = zf;
    int wrow0 = (wave < 4) ? (p*256 + wave*64) : (512 + p*256 + (wave-4)*64);
    gemm_strip(ldsp, LDS_X, Wqk, wrow0, l15, lg, acc);
#pragma unroll
    for (int nt=0; nt<4; nt++){
      int ch  = wrow0 + nt*16 + l15;
      int col = wave*64 + nt*16 + l15;
      float bias = qk_b[ch];
#pragma unroll
      for (int mt=0; mt<4; mt++)
#pragma unroll
        for (int i=0; i<4; i++){
          int r = mt*16 + lg*4 + i;
          if (r < 49)
            *(u16*)(ldsp + swz(LDS_QK, r, 1024u, (unsigned)(col*2))) = f2bf(acc[mt][nt][i] + bias);
        }
    }
  };
  auto attn_pass = [&](int p, f32x4 (&em)[4][2]){
    const int h = p*8 + wave;
    f32x4 s[4][4];
#pragma unroll
    for (int mt=0; mt<4; mt++)
#pragma unroll
      for (int nt=0; nt<4; nt++) s[mt][nt] = zf;
    short8 aq[4], bq[4];
#pragma unroll
    for (int mt=0; mt<4; mt++){
      int r = mt*16 + l15; if (r > 48) r = 48;
      aq[mt] = *(const short8*)(ldsp + swz(LDS_QK, r, 1024u, (unsigned)(wave*64 + lg*16)));
    }
#pragma unroll
    for (int nt=0; nt<4; nt++){
      int kt = nt*16 + l15; if (kt > 48) kt = 48;
      bq[nt] = *(const short8*)(ldsp + swz(LDS_QK, kt, 1024u, (unsigned)(512 + wave*64 + lg*16)));
    }
#pragma unroll
    for (int mt=0; mt<4; mt++)
#pragma unroll
      for (int nt=0; nt<4; nt++)
        s[mt][nt] = __builtin_amdgcn_mfma_f32_16x16x32_bf16(aq[mt], bq[nt], s[mt][nt], 0, 0, 0);
#pragma unroll
    for (int mt=0; mt<4; mt++)
#pragma unroll
      for (int nt=0; nt<4; nt++)
#pragma unroll
        for (int i=0; i<4; i++){
          int q  = mt*16 + lg*4 + i;
          int kt = nt*16 + l15;
          float v = s[mt][nt][i] * SCALE_F;
          if (kt < 49){
            int qc = (q > 48) ? 48 : q;
            int qi = qc / 7, qj = qc - qi*7;
            int ki = kt / 7, kj = kt - ki*7;
            int idx = (qi - ki + 6)*13 + (qj - kj + 6);
            v += bf2f(*(const u16*)(ldsp + LDS_RPB + (idx*16 + h)*2));
          } else v = -1e30f;
          s[mt][nt][i] = v;
        }
#pragma unroll
    for (int mt=0; mt<4; mt++)
#pragma unroll
      for (int i=0; i<4; i++){
        float m = fmaxf(fmaxf(s[mt][0][i], s[mt][1][i]), fmaxf(s[mt][2][i], s[mt][3][i]));
        m = fmaxf(m, __shfl_xor(m, 1)); m = fmaxf(m, __shfl_xor(m, 2));
        m = fmaxf(m, __shfl_xor(m, 4)); m = fmaxf(m, __shfl_xor(m, 8));
        float sum = 0.f;
#pragma unroll
        for (int nt=0; nt<4; nt++){ float e = __expf(s[mt][nt][i] - m); s[mt][nt][i] = e; sum += e; }
        sum += __shfl_xor(sum, 1); sum += __shfl_xor(sum, 2);
        sum += __shfl_xor(sum, 4); sum += __shfl_xor(sum, 8);
        float inv = 1.0f / sum;
#pragma unroll
        for (int nt=0; nt<4; nt++) s[mt][nt][i] *= inv;
      }
    __syncthreads();
    const unsigned ptb = LDS_QK + (unsigned)wave * 6272u;
#pragma unroll
    for (int mt=0; mt<4; mt++)
#pragma unroll
      for (int nt=0; nt<4; nt++)
#pragma unroll
        for (int i=0; i<4; i++){
          int q  = mt*16 + lg*4 + i;
          int kt = nt*16 + l15;
          if (kt < 49){
            u16 val = (q < 49) ? f2bf(s[mt][nt][i]) : (u16)0;
            *(u16*)(ldsp + ptb + (unsigned)kt*128u + (((unsigned)(q*2)) ^ (((unsigned)kt & 7u) << 4))) = val;
          }
        }
#pragma unroll
    for (int kk=0; kk<2; kk++){
      short8 pa[4];
#pragma unroll
      for (int mt=0; mt<4; mt++){
        int r = mt*16 + l15; if (r > 48) r = 48;
        pa[mt] = *(const short8*)(ldsp + ptb + (unsigned)r*128u + (((unsigned)(kk*64 + lg*16)) ^ (((unsigned)r & 7u) << 4)));
      }
      short8 vb[2];
#pragma unroll
      for (int nt=0; nt<2; nt++){
        int ch = h*32 + nt*16 + l15;
#pragma unroll
        for (int j=0; j<8; j++){
          int kt = kk*32 + lg*8 + j; if (kt > 48) kt = 48;
          vb[nt][j] = *(const short*)(ldsp + swz(LDS_V, kt, 1024u, (unsigned)(ch*2)));
        }
      }
#pragma unroll
      for (int mt=0; mt<4; mt++)
#pragma unroll
        for (int nt=0; nt<2; nt++)
          em[mt][nt] = __builtin_amdgcn_mfma_f32_16x16x32_bf16(pa[mt], vb[nt], em[mt][nt], 0, 0, 0);
    }
  };
  f32x4 em0[4][2], em1[4][2];
#pragma unroll
  for (int mt=0; mt<4; mt++)
#pragma unroll
    for (int nt=0; nt<2; nt++){ em0[mt][nt] = zf; em1[mt][nt] = zf; }
  qk_pass(0);
  __syncthreads();
  attn_pass(0, em0);
  __syncthreads();
  qk_pass(1);
  __syncthreads();
  attn_pass(1, em1);
  __syncthreads();
  for (int nh = 0; nh < 2; nh++){
    f32x4 acc[4][4];
#pragma unroll
    for (int mt=0; mt<4; mt++)
#pragma unroll
      for (int nt=0; nt<4; nt++) acc[mt][nt] = zf;
    int n0 = nh*512 + wave*64;
    gemm_strip(ldsp, LDS_X, Wwg, n0, l15, lg, acc);
#pragma unroll
    for (int nt=0; nt<4; nt++){
      int n  = n0 + nt*16 + l15;
      int pc = (n & 31)*32 + (n >> 5);
      unsigned cb = ((unsigned)(pc*2)) ^ (((unsigned)n & 7u) << 4);
#pragma unroll
      for (int mt=0; mt<4; mt++)
#pragma unroll
        for (int i=0; i<4; i++){
          int r = mt*16 + lg*4 + i;
          if (r < 49)
            *(u16*)(ldsp + LDS_PW + (unsigned)r*2048u + cb) = f2bf(acc[mt][nt][i]);
        }
    }
  }
  __syncthreads();
  auto em_store = [&](f32x4 (&em)[4][2], int h){
#pragma unroll
    for (int mt=0; mt<4; mt++)
#pragma unroll
      for (int nt=0; nt<2; nt++)
#pragma unroll
        for (int i=0; i<4; i++){
          int q = mt*16 + lg*4 + i;
          if (q < 49){
            int ch = h*32 + nt*16 + l15;
            *(u16*)(ldsp + swz(LDS_EM, q, 1024u, (unsigned)(ch*2))) = f2bf(em[mt][nt][i]);
          }
        }
  };
  em_store(em0, wave);
  em_store(em1, 8 + wave);
  __syncthreads();
  for (int t = wave; t < 49; t += 8){
    short8 ea = *(const short8*)(ldsp + swz(LDS_EM, t, 1024u, (unsigned)(l15*64 + lg*16)));
    f32x4 o[2];
#pragma unroll
    for (int nt=0; nt<2; nt++){
      int f = nt*16 + l15;
      short8 pb = *(const short8*)(ldsp + LDS_PW + (unsigned)t*2048u +
                    (((unsigned)((f*32 + lg*8)*2)) ^ (((unsigned)f & 7u) << 4)));
      o[nt] = __builtin_amdgcn_mfma_f32_16x16x32_bf16(ea, pb, zf, 0, 0, 0);
    }
#pragma unroll
    for (int nt=0; nt<2; nt++)
#pragma unroll
      for (int i=0; i<4; i++){
        int h2 = lg*4 + i;
        int ch = h2*32 + nt*16 + l15;
        *(u16*)(ldsp + swz(LDS_EM, t, 1024u, (unsigned)(ch*2))) = f2bf(o[nt][i]);
      }
  }
  __syncthreads();
  {
    f32x4 acc[4][4];
#pragma unroll
    for (int mt=0; mt<4; mt++)
#pragma unroll
      for (int nt=0; nt<4; nt++) acc[mt][nt] = zf;
    gemm_strip(ldsp, LDS_EM, Wproj, wave*64, l15, lg, acc);
    float* ob = out + (size_t)b * 49 * 512;
#pragma unroll
    for (int nt=0; nt<4; nt++){
      int n = wave*64 + nt*16 + l15;
      float bias = proj_b[n];
#pragma unroll
      for (int mt=0; mt<4; mt++)
#pragma unroll
        for (int i=0; i<4; i++){
          int r = mt*16 + lg*4 + i;
          if (r < 49) ob[r*512 + n] = acc[mt][nt][i] + bias;
        }
    }
  }
}

// =====================================================================
extern "C" void kernel_launch(void* const* d_in, const int* in_sizes, int n_in,
                              void* d_out, int out_size, void* d_ws, size_t ws_size,
                              hipStream_t stream){
  const float* x       = (const float*)d_in[0];
  const float* qk_w    = (const float*)d_in[1];
  const float* qk_b    = (const float*)d_in[2];
  const float* rev_v_w = (const float*)d_in[3];
  const float* rev_v_b = (const float*)d_in[4];
  const float* wg_w    = (const float*)d_in[5];
  const float* proj_w  = (const float*)d_in[6];
  const float* proj_b  = (const float*)d_in[7];
  const float* rpb     = (const float*)d_in[8];
  u16* ws = (u16*)d_ws;

  const unsigned long long BASE = 105906176ULL;
  int C = 0;
  for (int cand : {2048, 1024, 512, 256, 128}){
    if (BASE + (unsigned long long)cand * 301056ULL <= ws_size){ C = cand; break; }
  }
  if (C == 0){
    conv_w4<<<6144, 256, 0, stream>>>(qk_w, rev_v_w, wg_w, proj_w, ws);
    wa_main<<<2048, 512, 0, stream>>>(x, qk_b, rev_v_b, proj_b, rpb,
        ws, ws + 524288, ws + 786432, ws + 1310720, (float*)d_out);
    return;
  }

  u16* Wcat  = ws;
  u16* Wproj = ws + 1310720;
  u16* xb    = ws + 1572864;
  u16* qkvpw = ws + 52953088ULL;
  u16* o1    = qkvpw + (size_t)C * 49 * 2560;

  convk<<<25856, 256, 0, stream>>>(x, qk_w, rev_v_w, wg_w, proj_w, ws);

  const int nch = 2048 / C;
  const int mt128 = C * 49 / 128;
  for (int ch = 0; ch < nch; ch++){
    size_t t0 = (size_t)ch * C * 49;
    gemm128<20, 0><<<mt128 * 20, 256, 0, stream>>>(xb + t0*512, 512, Wcat,
        qk_b, rev_v_b, qkvpw, 2560);
    attn_fused<<<C, 512, 0, stream>>>(qkvpw, rpb, o1);
    gemm128<4, 1><<<mt128 * 4, 256, 0, stream>>>(o1, 512, Wproj,
        proj_b, (const float*)nullptr, (float*)d_out + t0*512, 512);
  }
  (void)Wcat; (void)Wproj;
}